// Round 10
// baseline (928.018 us; speedup 1.0000x reference)
//
#include <hip/hip_runtime.h>

// HeteroGAT: 2-layer bipartite GAT (heads=4,ch=25 concat + edge feat; then heads=1,ch=100).
// R6-R9: bf16 packed tables + LDS-staged gemms: 1242->991us.
// R10-R13: gather ILP + 256B row padding: 991->921us (FETCH 334->275MB; ~5%/round).
//      Counters: VALU 43%, ~82 cyc/edge (~35 VALU: 2 exps + logit math) -> co-limited
//      by VALU work and the random-load chain.
// R14: two-phase edges. Logit tables (aS/aD, 800KB each) are L2-RESIDENT; values
//      (12.8MB) are not. Precompute per-edge p=exp(leaky(aS[s]+aD[d]+w*ce)) in a
//      COALESCED kernel (fp32 [E][4] / [E]); gather loads p as a hot stream.
//      Gather inner loop: 1 random value u32 + 1 hot 8B p load + ~10 VALU (was ~30).
//      aS written bf16-rounded so p inputs match packed rows exactly; accumulation
//      order verbatim -> absmax unchanged (0.00390625).

#define NNODES 50000
#define NEDGES 800000
#define SCAN_T 1024
#define SCAN_NBLK ((NNODES + SCAN_T - 1) / SCAN_T)  // 49

typedef unsigned short u16;
typedef unsigned int u32;

__device__ __forceinline__ float b2f(u16 u) {
    union { u32 i; float f; } x;
    x.i = ((u32)u) << 16;
    return x.f;
}
__device__ __forceinline__ u16 f2b(float f) {  // RN-even
    union { float f; u32 i; } x;
    x.f = f;
    u32 r = x.i + 0x7FFFu + ((x.i >> 16) & 1u);
    return (u16)(r >> 16);
}

// ---------------- ce[h] = sum_c We[h*25+c]*ae[h*25+c] (edge-attn constant) ----------------
__global__ void ce_kernel(const float* __restrict__ WeA, const float* __restrict__ aeA,
                          const float* __restrict__ WeB, const float* __restrict__ aeB,
                          float* __restrict__ ce /*[8]: 0..3=AB, 4..7=BA*/) {
    const float* We = blockIdx.x ? WeB : WeA;
    const float* ae = blockIdx.x ? aeB : aeA;
    __shared__ float s[4];
    int tid = threadIdx.x;
    if (tid < 4) s[tid] = 0.f;
    __syncthreads();
    if (tid < 100) atomicAdd(&s[tid / 25], We[tid] * ae[tid]);
    __syncthreads();
    if (tid < 4) ce[blockIdx.x * 4 + tid] = s[tid];
}

// ---------------- CSR build ----------------
__global__ void count_kernel(const int* __restrict__ eiA, const int* __restrict__ eiB,
                             int E, int* cntA, int* cntB) {
    int i = blockIdx.x * blockDim.x + threadIdx.x;
    if (i < E) atomicAdd(&cntA[eiA[E + i]], 1);
    else if (i < 2 * E) atomicAdd(&cntB[eiB[E + (i - E)]], 1);
}

__global__ __launch_bounds__(SCAN_T) void scanA_kernel(
    const int* __restrict__ cntA, const int* __restrict__ cntB,
    int* __restrict__ roA, int* __restrict__ roB, int* __restrict__ partial, int N) {
    const int dir = blockIdx.y;
    const int* cnt = dir ? cntB : cntA;
    int* ro = dir ? roB : roA;
    const int tid = threadIdx.x;
    const int i = blockIdx.x * SCAN_T + tid;
    __shared__ int sm[SCAN_T];
    sm[tid] = (i < N) ? cnt[i] : 0;
    __syncthreads();
    for (int off = 1; off < SCAN_T; off <<= 1) {
        int t = (tid >= off) ? sm[tid - off] : 0;
        __syncthreads();
        sm[tid] += t;
        __syncthreads();
    }
    if (i < N) ro[i + 1] = sm[tid];
    if (tid == SCAN_T - 1) partial[dir * 64 + blockIdx.x] = sm[tid];
}

__global__ void scanB_kernel(int* __restrict__ partial, int nblk) {
    __shared__ int sm[128];
    const int tid = threadIdx.x;
    sm[tid] = ((tid & 63) < nblk) ? partial[tid] : 0;
    __syncthreads();
    if (tid < 2) {
        int run = 0;
        for (int b = 0; b < nblk; ++b) {
            int t = sm[tid * 64 + b];
            sm[tid * 64 + b] = run;
            run += t;
        }
    }
    __syncthreads();
    partial[tid] = sm[tid];
}

__global__ __launch_bounds__(SCAN_T) void scanC_kernel(
    const int* __restrict__ cntA, const int* __restrict__ cntB,
    int* __restrict__ roA, int* __restrict__ roB,
    int* __restrict__ curA, int* __restrict__ curB,
    const int* __restrict__ partial, int N) {
    const int dir = blockIdx.y;
    const int* cnt = dir ? cntB : cntA;
    int* ro = dir ? roB : roA;
    int* cur = dir ? curB : curA;
    const int poff = partial[dir * 64 + blockIdx.x];
    const int i = blockIdx.x * SCAN_T + threadIdx.x;
    if (i < N) {
        int c = cnt[i];
        int r = ro[i + 1] + poff;
        ro[i + 1] = r;
        cur[i] = r - c;
        if (i == 0) ro[0] = 0;
    }
}

__global__ void fill_kernel(const int* __restrict__ eiA, const int* __restrict__ eiB,
                            const float* __restrict__ wA, const float* __restrict__ wB,
                            int E, int* curA, int* curB,
                            int* __restrict__ ssA, int* __restrict__ ssB,
                            int* __restrict__ sdA, int* __restrict__ sdB,
                            float* __restrict__ swA, float* __restrict__ swB) {
    int i = blockIdx.x * blockDim.x + threadIdx.x;
    if (i < E) {
        int s = eiA[i], d = eiA[E + i];
        int pos = atomicAdd(&curA[d], 1);
        ssA[pos] = s; sdA[pos] = d; swA[pos] = wA[i];
    } else if (i < 2 * E) {
        int j = i - E;
        int s = eiB[j], d = eiB[E + j];
        int pos = atomicAdd(&curB[d], 1);
        ssB[pos] = s; sdB[pos] = d; swB[pos] = wB[j];
    }
}

// ---------------- GEMM [N,K]x[K,100] + fused att ----------------
// 128 nodes/block; lane owns nodes (lane, lane+64); wave w owns cols [25w,25w+25).
// R8/R9: BOTH operands staged via LDS per 32-wide K-chunk, double-buffered.
// R13: packed-table output rows padded to 256B (node stride 64 u32).
// R14: src roles (H!=null) ALSO write a compact att table, bf16-ROUNDED (so the
//      edge-p precompute sees exactly the packed-row values).
struct GemmArgs {
    const float* X;
    const float* W;
    const float* a;
    void* H;
    float* att;
};

template <int K, int HEADS>
__global__ __launch_bounds__(256, 2) void gemm_att_kernel(
    GemmArgs g0, GemmArgs g1, GemmArgs g2, GemmArgs g3, int N) {
    const GemmArgs ga[4] = {g0, g1, g2, g3};
    const GemmArgs g = ga[blockIdx.y];
    constexpr int XS_STRIDE = 33;
    constexpr int XS_BUF = 128 * XS_STRIDE;     // 4224 floats per buffer
    constexpr int WS_STRIDE = 28;               // 112B rows -> 16B aligned slices
    constexpr int WS_WAVE = 32 * WS_STRIDE;     // 896 floats per wave slice
    constexpr int WS_BUF = 4 * WS_WAVE;         // 3584 floats per buffer
    constexpr int SMEM_BYTES = (2 * XS_BUF + 2 * WS_BUF) * 4;  // 62464
    __shared__ __align__(16) char smem[SMEM_BYTES];
    const int tid = threadIdx.x;
    const int lane = tid & 63;
    const int w = tid >> 6;
    const int node0 = blockIdx.x * 128;
    const int nA = node0 + lane;
    const int nB = node0 + 64 + lane;
    const bool vA = nA < N, vB = nB < N;

    const int c0 = __builtin_amdgcn_readfirstlane(25 * w);  // wave-uniform

    float acc0[25], acc1[25];
#pragma unroll
    for (int j = 0; j < 25; ++j) { acc0[j] = 0.f; acc1[j] = 0.f; }

    float* Xs = (float*)smem;
    float* Wsh = (float*)smem + 2 * XS_BUF;
    float4 rv[4];
    float wv[13];

    auto issue_x = [&](int k0) {
#pragma unroll
        for (int r = 0; r < 4; ++r) {
            const int s = tid + r * 256;
            const int n = s >> 3;
            const int ko = (s & 7) * 4;
            int row = node0 + n;
            if (row >= N) row = N - 1;  // valid addr; values masked in epilogue
            const float* xp = g.X + (size_t)row * K + k0 + ko;
            if constexpr (K % 32 == 0) {
                rv[r] = *(const float4*)xp;
            } else {
                const int kb = k0 + ko;
                float4 v = make_float4(0.f, 0.f, 0.f, 0.f);
                if (kb + 3 < K) {
                    v = *(const float4*)xp;
                } else {
                    if (kb < K) v.x = xp[0];
                    if (kb + 1 < K) v.y = xp[1];
                    if (kb + 2 < K) v.z = xp[2];
                }
                rv[r] = v;
            }
        }
    };
    auto write_x = [&](int buf) {
#pragma unroll
        for (int r = 0; r < 4; ++r) {
            const int s = tid + r * 256;
            const int n = s >> 3;
            const int ko = (s & 7) * 4;
            float* dst = Xs + buf * XS_BUF + n * XS_STRIDE + ko;
            dst[0] = rv[r].x;
            dst[1] = rv[r].y;
            dst[2] = rv[r].z;
            dst[3] = rv[r].w;
        }
    };
    auto issue_w = [&](int k0, int kc) {
        const int lim = kc * 100;
#pragma unroll
        for (int r = 0; r < 13; ++r) {
            const int e = tid + r * 256;
            wv[r] = (e < lim) ? g.W[(size_t)k0 * 100 + e] : 0.f;
        }
    };
    auto write_w = [&](int buf, int kc) {
        const int lim = kc * 100;
#pragma unroll
        for (int r = 0; r < 13; ++r) {
            const int e = tid + r * 256;
            if (e < lim) {
                const int k = e / 100;
                const int j = e - k * 100;
                const int hd = j / 25;
                const int jj = j - hd * 25;
                Wsh[buf * WS_BUF + hd * WS_WAVE + k * WS_STRIDE + jj] = wv[r];
            }
        }
    };

    constexpr int C = (K + 31) / 32;
    {
        const int kc0 = (K < 32) ? K : 32;
        issue_x(0);
        issue_w(0, kc0);
        write_x(0);
        write_w(0, kc0);
    }
    __syncthreads();
    for (int c = 0; c < C; ++c) {
        const int k0 = c * 32;
        const int kc = (K - k0 < 32) ? (K - k0) : 32;
        const int kcn = (K - k0 - 32 < 32) ? (K - k0 - 32) : 32;
        if (c + 1 < C) {
            issue_x(k0 + 32);
            issue_w(k0 + 32, kcn);
        }
        const float* x0p = Xs + (c & 1) * XS_BUF + lane * XS_STRIDE;
        const float* x1p = x0p + 64 * XS_STRIDE;
        const float* wp = Wsh + (c & 1) * WS_BUF + w * WS_WAVE;
#pragma unroll 4
        for (int kk = 0; kk < kc; ++kk) {
            const float xs0 = x0p[kk];
            const float xs1 = x1p[kk];
            float wr[25];
#pragma unroll
            for (int j = 0; j < 25; ++j) wr[j] = wp[kk * WS_STRIDE + j];
#pragma unroll
            for (int j = 0; j < 25; ++j) {
                acc0[j] = fmaf(xs0, wr[j], acc0[j]);
                acc1[j] = fmaf(xs1, wr[j], acc1[j]);
            }
        }
        if (c + 1 < C) {
            __syncthreads();  // all waves done reading buf (c+1)&1 before overwrite
            write_x((c + 1) & 1);
            write_w((c + 1) & 1, kcn);
        }
        __syncthreads();
    }

    float ap0 = 0.f, ap1 = 0.f;
#pragma unroll
    for (int j = 0; j < 25; ++j) {
        const float av = g.a[c0 + j];
        ap0 = fmaf(acc0[j], av, ap0);
        ap1 = fmaf(acc1[j], av, ap1);
    }

    const int rem = N - node0;
    if (HEADS == 4) {
        if (g.att != nullptr) {  // att table: dst role raw; src role bf16-rounded
            const float w0 = (g.H != nullptr) ? b2f(f2b(ap0)) : ap0;
            const float w1 = (g.H != nullptr) ? b2f(f2b(ap1)) : ap1;
            if (vA) g.att[(size_t)nA * 4 + w] = w0;
            if (vB) g.att[(size_t)nB * 4 + w] = w1;
        }
        if (g.H != nullptr) {  // src role: rows of 128 u16 (104 payload), stride 64 u32
            u16* sh = (u16*)smem;
            u32* sh32 = (u32*)smem;
            // chunk A
#pragma unroll
            for (int j = 0; j < 25; ++j) sh[lane * 106 + c0 + j] = f2b(acc0[j]);
            sh[lane * 106 + 100 + w] = f2b(ap0);
            __syncthreads();
            {
                const int limA = ((rem < 64) ? rem : 64) * 52;
                u32* Hb = (u32*)g.H + (size_t)node0 * 64;
                for (int i = tid; i < 64 * 52; i += 256) {
                    if (i < limA) {
                        int nd = i / 52;
                        int off = i - nd * 52;
                        Hb[nd * 64 + off] = sh32[nd * 53 + off];
                    }
                }
            }
            __syncthreads();
            // chunk B
#pragma unroll
            for (int j = 0; j < 25; ++j) sh[lane * 106 + c0 + j] = f2b(acc1[j]);
            sh[lane * 106 + 100 + w] = f2b(ap1);
            __syncthreads();
            {
                const int remB = rem - 64;
                const int limB = ((remB < 64) ? (remB < 0 ? 0 : remB) : 64) * 52;
                u32* Hb = (u32*)g.H + (size_t)(node0 + 64) * 64;
                for (int i = tid; i < 64 * 52; i += 256) {
                    if (i < limB) {
                        int nd = i / 52;
                        int off = i - nd * 52;
                        Hb[nd * 64 + off] = sh32[nd * 53 + off];
                    }
                }
            }
        }
    } else {
        // HEADS==1: rows of 128 u16 (100 payload), node stride 64 u32
        u16* sh = (u16*)smem;
        u32* sh32 = (u32*)smem;
        float* attp = (float*)(smem + 64 * 102 * 2);
        attp[w * 128 + lane] = ap0;
        attp[w * 128 + 64 + lane] = ap1;
        if (g.H != nullptr) {
            // chunk A
#pragma unroll
            for (int j = 0; j < 25; ++j) sh[lane * 102 + c0 + j] = f2b(acc0[j]);
            __syncthreads();
            {
                const int limA = ((rem < 64) ? rem : 64) * 50;
                u32* Hb = (u32*)g.H + (size_t)node0 * 64;
                for (int i = tid; i < 64 * 50; i += 256) {
                    if (i < limA) {
                        int nd = i / 50;
                        int off = i - nd * 50;
                        Hb[nd * 64 + off] = sh32[nd * 51 + off];
                    }
                }
                if (tid < 128 && node0 + tid < N)
                    g.att[node0 + tid] =
                        attp[tid] + attp[128 + tid] + attp[256 + tid] + attp[384 + tid];
            }
            __syncthreads();
            // chunk B
#pragma unroll
            for (int j = 0; j < 25; ++j) sh[lane * 102 + c0 + j] = f2b(acc1[j]);
            __syncthreads();
            {
                const int remB = rem - 64;
                const int limB = ((remB < 64) ? (remB < 0 ? 0 : remB) : 64) * 50;
                u32* Hb = (u32*)g.H + (size_t)(node0 + 64) * 64;
                for (int i = tid; i < 64 * 50; i += 256) {
                    if (i < limB) {
                        int nd = i / 50;
                        int off = i - nd * 50;
                        Hb[nd * 64 + off] = sh32[nd * 51 + off];
                    }
                }
            }
        } else {
            __syncthreads();
            if (tid < 128 && node0 + tid < N)
                g.att[node0 + tid] =
                    attp[tid] + attp[128 + tid] + attp[256 + tid] + attp[384 + tid];
        }
    }
}

// ---------------- R14: coalesced per-edge logit/exp precompute ----------------
struct EdgeP4Args {
    const int* ss;
    const int* sd;
    const float* sw;
    const float* aS;  // [Ns,4] bf16-rounded fp32
    const float* aD;  // [Nd,4] fp32
    const float* ce;  // [4]
    float* p4;        // [E,4] fp32
};

__global__ void edge_p4_kernel(EdgeP4Args a0, EdgeP4Args a1, int E) {
    const EdgeP4Args a = blockIdx.y ? a1 : a0;
    const int e = blockIdx.x * 256 + threadIdx.x;
    if (e >= E) return;
    const int s = a.ss[e];
    const int d = a.sd[e];
    const float w = a.sw[e];
    const float4 as4 = *(const float4*)(a.aS + (size_t)s * 4);  // L2-resident tables
    const float4 ad4 = *(const float4*)(a.aD + (size_t)d * 4);
    float4 p;
    float l;
    l = as4.x + ad4.x + w * a.ce[0]; l = fmaxf(l, 0.2f * l); p.x = __expf(l);
    l = as4.y + ad4.y + w * a.ce[1]; l = fmaxf(l, 0.2f * l); p.y = __expf(l);
    l = as4.z + ad4.z + w * a.ce[2]; l = fmaxf(l, 0.2f * l); p.z = __expf(l);
    l = as4.w + ad4.w + w * a.ce[3]; l = fmaxf(l, 0.2f * l); p.w = __expf(l);
    *(float4*)(a.p4 + (size_t)e * 4) = p;
}

struct EdgeP1Args {
    const int* ss;
    const int* sd;
    const float* aS;  // [Ns] fp32
    const float* aD;  // [Nd] fp32
    float* p1;        // [E] fp32
};

__global__ void edge_p1_kernel(EdgeP1Args a0, EdgeP1Args a1, int E) {
    const EdgeP1Args a = blockIdx.y ? a1 : a0;
    const int e = blockIdx.x * 256 + threadIdx.x;
    if (e >= E) return;
    const int s = a.ss[e];
    const int d = a.sd[e];
    float l = a.aS[s] + a.aD[d];
    l = fmaxf(l, 0.2f * l);
    a.p1[e] = __expf(l);
}

// ---------------- layer-1 gather: wave per dst node, 256B-aligned bf16 src rows ----------------
// R14: per edge, 1 random value u32 + 1 hot 8B p-pair load; logit/exp precomputed.
struct Gather4Args {
    const int* ro;
    const int* ss;
    const u16* hp;     // [Ns][128] bf16: 0..99 h
    const float* p4;   // [E][4] fp32 edge probs (CSR order)
    const float* bias; // [100]
    float* outp;       // [Nd,100]
};

__global__ __launch_bounds__(256) void gather4_kernel(Gather4Args ga0, Gather4Args ga1, int Nd) {
    const Gather4Args ga[2] = {ga0, ga1};
    const Gather4Args g = ga[blockIdx.y];
    int wid = (int)((blockIdx.x * blockDim.x + threadIdx.x) >> 6);
    if (wid >= Nd) return;
    const int n = __builtin_amdgcn_readfirstlane(wid);
    const int lane = threadIdx.x & 63;
    const int beg = g.ro[n], end = g.ro[n + 1];
    const bool act = (lane < 50);
    const int cc0 = act ? 2 * lane : 0;   // channels (cc0, cc0+1)
    const int h0 = cc0 / 25;
    const int h1 = (cc0 + 1) / 25;        // same head-pair as h0 (proof: cc0 even)
    const int aoff = 2 * (h0 >> 1);       // float offset of head-pair in p4 row
    float acc0 = 0.f, acc1 = 0.f, d0 = 0.f, d1 = 0.f;

    auto edge = [&](u32 va, float2 pp, float& p0o, float& p1o) {
        const float p0 = (h0 & 1) ? pp.y : pp.x;
        const float p1 = (h1 & 1) ? pp.y : pp.x;
        acc0 = fmaf(p0, b2f((u16)va), acc0);
        acc1 = fmaf(p1, b2f((u16)(va >> 16)), acc1);
        p0o = p0;
        p1o = p1;
    };

    struct G4 { u32 va0, va1, va2, va3; float2 pp0, pp1, pp2, pp3; };
    auto load4 = [&](int off) -> G4 {
        G4 r;
        const int o = __builtin_amdgcn_readfirstlane(off);
        const int s0 = g.ss[o];
        const int s1 = g.ss[o + 1];
        const int s2 = g.ss[o + 2];
        const int s3 = g.ss[o + 3];
        r.pp0 = *(const float2*)(g.p4 + (size_t)o * 4 + aoff);
        r.pp1 = *(const float2*)(g.p4 + (size_t)(o + 1) * 4 + aoff);
        r.pp2 = *(const float2*)(g.p4 + (size_t)(o + 2) * 4 + aoff);
        r.pp3 = *(const float2*)(g.p4 + (size_t)(o + 3) * 4 + aoff);
        r.va0 = *(const u32*)(g.hp + (size_t)s0 * 128 + cc0);
        r.va1 = *(const u32*)(g.hp + (size_t)s1 * 128 + cc0);
        r.va2 = *(const u32*)(g.hp + (size_t)s2 * 128 + cc0);
        r.va3 = *(const u32*)(g.hp + (size_t)s3 * 128 + cc0);
        return r;
    };
    auto compute4 = [&](const G4& e) {
        float pa0, pa1, pb0, pb1;
        edge(e.va0, e.pp0, pa0, pa1);
        edge(e.va1, e.pp1, pb0, pb1);
        d0 += pa0 + pb0;
        d1 += pa1 + pb1;
        edge(e.va2, e.pp2, pa0, pa1);
        edge(e.va3, e.pp3, pb0, pb1);
        d0 += pa0 + pb0;
        d1 += pa1 + pb1;
    };

    int i = beg;
    const int last4 = beg + ((end - beg) & ~3);
    const int ng = (last4 - beg) >> 2;
    if (ng >= 2) {  // 2-deep pipeline
        G4 cur = load4(i);
        G4 nxt = load4(i + 4);
        i += 8;
        for (; i < last4; i += 4) {
            G4 nn = load4(i);
            __builtin_amdgcn_sched_barrier(0);  // keep prefetch above compute
            compute4(cur);
            cur = nxt;
            nxt = nn;
        }
        compute4(cur);
        compute4(nxt);
    } else if (ng == 1) {
        G4 cur = load4(i);
        compute4(cur);
        i += 4;
    }
    if (i + 1 < end) {  // 2-3 remain -> pair
        const int o = __builtin_amdgcn_readfirstlane(i);
        const int s0 = g.ss[o], s1 = g.ss[o + 1];
        const float2 pp0 = *(const float2*)(g.p4 + (size_t)o * 4 + aoff);
        const float2 pp1 = *(const float2*)(g.p4 + (size_t)(o + 1) * 4 + aoff);
        const u32 va0 = *(const u32*)(g.hp + (size_t)s0 * 128 + cc0);
        const u32 va1 = *(const u32*)(g.hp + (size_t)s1 * 128 + cc0);
        float pa0, pa1, pb0, pb1;
        edge(va0, pp0, pa0, pa1);
        edge(va1, pp1, pb0, pb1);
        d0 += pa0 + pb0;
        d1 += pa1 + pb1;
        i += 2;
    }
    if (i < end) {  // single
        const int o = __builtin_amdgcn_readfirstlane(i);
        const int s0 = g.ss[o];
        const float2 pp0 = *(const float2*)(g.p4 + (size_t)o * 4 + aoff);
        const u32 va0 = *(const u32*)(g.hp + (size_t)s0 * 128 + cc0);
        float pa0, pa1;
        edge(va0, pp0, pa0, pa1);
        d0 += pa0;
        d1 += pa1;
    }

    if (act) {
        float r0 = (end > beg) ? acc0 / d0 : 0.f;
        float r1 = (end > beg) ? acc1 / d1 : 0.f;
        r0 += g.bias[cc0];
        r0 = (r0 > 0.f) ? r0 : (__expf(r0) - 1.f);  // elu
        r1 += g.bias[cc0 + 1];
        r1 = (r1 > 0.f) ? r1 : (__expf(r1) - 1.f);
        *(float2*)(g.outp + (size_t)n * 100 + cc0) = make_float2(r0, r1);
    }
}

// ---------------- layer-2 gather: wave per dst node, heads=1, 256B-aligned bf16 rows ----------------
// R14: p precomputed; scalar-loaded per edge (wave-uniform).
struct Gather1Args {
    const int* ro;
    const int* ss;
    const u16* hp;     // [Ns][128] bf16: 0..99 payload
    const float* p1;   // [E] fp32 edge probs (CSR order)
    const float* bias; // [100]
    float* outp;       // [Nd,100]
};

__global__ __launch_bounds__(256) void gather1_kernel(Gather1Args ga0, Gather1Args ga1, int Nd) {
    const Gather1Args ga[2] = {ga0, ga1};
    const Gather1Args g = ga[blockIdx.y];
    int wid = (int)((blockIdx.x * blockDim.x + threadIdx.x) >> 6);
    if (wid >= Nd) return;
    const int n = __builtin_amdgcn_readfirstlane(wid);
    const int lane = threadIdx.x & 63;
    const int beg = g.ro[n], end = g.ro[n + 1];
    const bool act = (lane < 50);
    const int cc0 = act ? 2 * lane : 0;
    float acc0 = 0.f, acc1 = 0.f, d0 = 0.f;

    auto edge = [&](u32 va, float p) {
        acc0 = fmaf(p, b2f((u16)va), acc0);
        acc1 = fmaf(p, b2f((u16)(va >> 16)), acc1);
    };

    struct G1 { u32 va0, va1, va2, va3; float p0, p1, p2, p3; };
    auto load4 = [&](int off) -> G1 {
        G1 r;
        const int o = __builtin_amdgcn_readfirstlane(off);
        const int s0 = g.ss[o];
        const int s1 = g.ss[o + 1];
        const int s2 = g.ss[o + 2];
        const int s3 = g.ss[o + 3];
        r.p0 = g.p1[o];
        r.p1 = g.p1[o + 1];
        r.p2 = g.p1[o + 2];
        r.p3 = g.p1[o + 3];
        r.va0 = *(const u32*)(g.hp + (size_t)s0 * 128 + cc0);
        r.va1 = *(const u32*)(g.hp + (size_t)s1 * 128 + cc0);
        r.va2 = *(const u32*)(g.hp + (size_t)s2 * 128 + cc0);
        r.va3 = *(const u32*)(g.hp + (size_t)s3 * 128 + cc0);
        return r;
    };
    auto compute4 = [&](const G1& e) {
        edge(e.va0, e.p0);
        edge(e.va1, e.p1);
        d0 += e.p0 + e.p1;
        edge(e.va2, e.p2);
        edge(e.va3, e.p3);
        d0 += e.p2 + e.p3;
    };

    int i = beg;
    const int last4 = beg + ((end - beg) & ~3);
    const int ng = (last4 - beg) >> 2;
    if (ng >= 2) {  // 2-deep pipeline
        G1 cur = load4(i);
        G1 nxt = load4(i + 4);
        i += 8;
        for (; i < last4; i += 4) {
            G1 nn = load4(i);
            __builtin_amdgcn_sched_barrier(0);  // keep prefetch above compute
            compute4(cur);
            cur = nxt;
            nxt = nn;
        }
        compute4(cur);
        compute4(nxt);
    } else if (ng == 1) {
        G1 cur = load4(i);
        compute4(cur);
        i += 4;
    }
    if (i + 1 < end) {  // 2-3 remain -> pair
        const int o = __builtin_amdgcn_readfirstlane(i);
        const int s0 = g.ss[o], s1 = g.ss[o + 1];
        const float p0 = g.p1[o], p1v = g.p1[o + 1];
        const u32 va0 = *(const u32*)(g.hp + (size_t)s0 * 128 + cc0);
        const u32 va1 = *(const u32*)(g.hp + (size_t)s1 * 128 + cc0);
        edge(va0, p0);
        edge(va1, p1v);
        d0 += p0 + p1v;
        i += 2;
    }
    if (i < end) {  // single
        const int o = __builtin_amdgcn_readfirstlane(i);
        const int s0 = g.ss[o];
        const float p0 = g.p1[o];
        const u32 va0 = *(const u32*)(g.hp + (size_t)s0 * 128 + cc0);
        edge(va0, p0);
        d0 += p0;
    }

    if (act) {
        float r0 = (end > beg) ? acc0 / d0 : 0.f;
        float r1 = (end > beg) ? acc1 / d0 : 0.f;
        r0 += g.bias[cc0];
        r1 += g.bias[cc0 + 1];
        *(float2*)(g.outp + (size_t)n * 100 + cc0) = make_float2(r0, r1);
    }
}

extern "C" void kernel_launch(void* const* d_in, const int* in_sizes, int n_in,
                              void* d_out, int out_size, void* d_ws, size_t ws_size,
                              hipStream_t stream) {
    const float* x_A   = (const float*)d_in[0];
    const float* x_B   = (const float*)d_in[1];
    const int*   ei_AB = (const int*)d_in[2];
    const int*   ei_BA = (const int*)d_in[3];
    const float* w_AB  = (const float*)d_in[4];
    const float* w_BA  = (const float*)d_in[5];
    const float* l1AB_Ws = (const float*)d_in[6];
    const float* l1AB_Wd = (const float*)d_in[7];
    const float* l1AB_as = (const float*)d_in[8];
    const float* l1AB_ad = (const float*)d_in[9];
    const float* l1AB_We = (const float*)d_in[10];
    const float* l1AB_ae = (const float*)d_in[11];
    const float* l1AB_b  = (const float*)d_in[12];
    const float* l2AB_Ws = (const float*)d_in[13];
    const float* l2AB_Wd = (const float*)d_in[14];
    const float* l2AB_as = (const float*)d_in[15];
    const float* l2AB_ad = (const float*)d_in[16];
    const float* l2AB_b  = (const float*)d_in[17];
    const float* l1BA_Ws = (const float*)d_in[18];
    const float* l1BA_Wd = (const float*)d_in[19];
    const float* l1BA_as = (const float*)d_in[20];
    const float* l1BA_ad = (const float*)d_in[21];
    const float* l1BA_We = (const float*)d_in[22];
    const float* l1BA_ae = (const float*)d_in[23];
    const float* l1BA_b  = (const float*)d_in[24];
    const float* l2BA_Ws = (const float*)d_in[25];
    const float* l2BA_Wd = (const float*)d_in[26];
    const float* l2BA_as = (const float*)d_in[27];
    const float* l2BA_ad = (const float*)d_in[28];
    const float* l2BA_b  = (const float*)d_in[29];

    const int N = NNODES, E = NEDGES;

    // ---- workspace carve (4-byte elements, 64-element aligned) ----
    size_t o = 0;
    auto alloc = [&](size_t n) { size_t r = o; o += (n + 63) & ~(size_t)63; return r; };
    size_t cntA = alloc(N), cntB = alloc(N);
    size_t roA = alloc(N + 1), roB = alloc(N + 1);
    size_t curA = alloc(N), curB = alloc(N);
    size_t ssA = alloc(E), ssB = alloc(E);
    size_t sdA = alloc(E), sdB = alloc(E);
    size_t swA = alloc(E), swB = alloc(E);
    size_t ce8 = alloc(8);
    size_t part = alloc(128);
    size_t pHAB = alloc((size_t)N * 64);  // packed bf16 [N][128] as uints (256B rows)
    size_t pHBA = alloc((size_t)N * 64);
    size_t ad1B = alloc((size_t)N * 4), ad1A = alloc((size_t)N * 4);
    size_t aS1AB = alloc((size_t)N * 4), aS1BA = alloc((size_t)N * 4);
    size_t p4AB = alloc((size_t)E * 4), p4BA = alloc((size_t)E * 4);
    size_t hA1 = alloc((size_t)N * 100), hB1 = alloc((size_t)N * 100);
    size_t H2AB = alloc((size_t)N * 64);  // packed bf16 [N][128] as uints (256B rows)
    size_t H2BA = alloc((size_t)N * 64);
    size_t as2AB = alloc(N), as2BA = alloc(N);
    size_t ad2AB = alloc(N), ad2BA = alloc(N);
    size_t p1AB = alloc(E), p1BA = alloc(E);
    (void)ws_size;

    float* wsf = (float*)d_ws;
    int*   wsi = (int*)d_ws;
    u32*   wsu = (u32*)d_ws;

    // zero edge-count histograms (cntA..cntB contiguous span)
    hipMemsetAsync(wsi + cntA, 0, sizeof(int) * (cntB + N - cntA), stream);

    ce_kernel<<<2, 128, 0, stream>>>(l1AB_We, l1AB_ae, l1BA_We, l1BA_ae, wsf + ce8);

    const int eb = (2 * E + 255) / 256;
    const int eb1 = (E + 255) / 256;
    count_kernel<<<eb, 256, 0, stream>>>(ei_AB, ei_BA, E, wsi + cntA, wsi + cntB);
    scanA_kernel<<<dim3(SCAN_NBLK, 2), SCAN_T, 0, stream>>>(
        wsi + cntA, wsi + cntB, wsi + roA, wsi + roB, wsi + part, N);
    scanB_kernel<<<1, 128, 0, stream>>>(wsi + part, SCAN_NBLK);
    scanC_kernel<<<dim3(SCAN_NBLK, 2), SCAN_T, 0, stream>>>(
        wsi + cntA, wsi + cntB, wsi + roA, wsi + roB, wsi + curA, wsi + curB, wsi + part, N);
    fill_kernel<<<eb, 256, 0, stream>>>(ei_AB, ei_BA, w_AB, w_BA, E, wsi + curA, wsi + curB,
                                        wsi + ssA, wsi + ssB, wsi + sdA, wsi + sdB,
                                        wsf + swA, wsf + swB);

    const int gb = (N + 127) / 128;  // 391
    // layer-1 node transforms (src roles -> packed tables + rounded aS; dst roles -> a_dst)
    {
        GemmArgs g0 = {x_A, l1AB_Ws, l1AB_as, (void*)(wsu + pHAB), wsf + aS1AB};
        GemmArgs g1 = {x_B, l1AB_Wd, l1AB_ad, nullptr, wsf + ad1B};
        GemmArgs g2 = {x_B, l1BA_Ws, l1BA_as, (void*)(wsu + pHBA), wsf + aS1BA};
        GemmArgs g3 = {x_A, l1BA_Wd, l1BA_ad, nullptr, wsf + ad1A};
        gemm_att_kernel<128, 4><<<dim3(gb, 4), 256, 0, stream>>>(g0, g1, g2, g3, N);
    }

    // per-edge probability precompute (coalesced; aS/aD tables L2-resident)
    {
        EdgeP4Args a0 = {wsi + ssA, wsi + sdA, wsf + swA, wsf + aS1AB, wsf + ad1B,
                         wsf + ce8, wsf + p4AB};
        EdgeP4Args a1 = {wsi + ssB, wsi + sdB, wsf + swB, wsf + aS1BA, wsf + ad1A,
                         wsf + ce8 + 4, wsf + p4BA};
        edge_p4_kernel<<<dim3(eb1, 2), 256, 0, stream>>>(a0, a1, E);
    }

    const int wb = (N + 3) / 4;  // wave per node, 4 waves/block
    {
        Gather4Args g0 = {wsi + roA, wsi + ssA, (const u16*)(wsu + pHAB), wsf + p4AB,
                          l1AB_b, wsf + hB1};
        Gather4Args g1 = {wsi + roB, wsi + ssB, (const u16*)(wsu + pHBA), wsf + p4BA,
                          l1BA_b, wsf + hA1};
        gather4_kernel<<<dim3(wb, 2), 256, 0, stream>>>(g0, g1, N);
    }

    // layer-2 node transforms (src roles -> packed bf16 H + as; dst roles -> ad only)
    {
        GemmArgs g0 = {wsf + hA1, l2AB_Ws, l2AB_as, (void*)(wsu + H2AB), wsf + as2AB};
        GemmArgs g1 = {wsf + hB1, l2AB_Wd, l2AB_ad, nullptr, wsf + ad2AB};
        GemmArgs g2 = {wsf + hB1, l2BA_Ws, l2BA_as, (void*)(wsu + H2BA), wsf + as2BA};
        GemmArgs g3 = {wsf + hA1, l2BA_Wd, l2BA_ad, nullptr, wsf + ad2BA};
        gemm_att_kernel<100, 1><<<dim3(gb, 4), 256, 0, stream>>>(g0, g1, g2, g3, N);
    }

    // layer-2 per-edge probability precompute
    {
        EdgeP1Args a0 = {wsi + ssA, wsi + sdA, wsf + as2AB, wsf + ad2AB, wsf + p1AB};
        EdgeP1Args a1 = {wsi + ssB, wsi + sdB, wsf + as2BA, wsf + ad2BA, wsf + p1BA};
        edge_p1_kernel<<<dim3(eb1, 2), 256, 0, stream>>>(a0, a1, E);
    }

    float* out = (float*)d_out;
    // oA = BA direction (dst in A) -> d_out[0..5M); oB = AB direction -> d_out[5M..10M)
    {
        Gather1Args g0 = {wsi + roA, wsi + ssA, (const u16*)(wsu + H2AB), wsf + p1AB,
                          l2AB_b, out + (size_t)N * 100};
        Gather1Args g1 = {wsi + roB, wsi + ssB, (const u16*)(wsu + H2BA), wsf + p1BA,
                          l2BA_b, out};
        gather1_kernel<<<dim3(wb, 2), 256, 0, stream>>>(g0, g1, N);
    }
}